// Round 12
// baseline (386.809 us; speedup 1.0000x reference)
//
#include <hip/hip_runtime.h>

#define K_DIM 4096
#define N_DIM 8192
#define PREFIX 1024             // prefix columns for the underflow test
#define TAILC (N_DIM - PREFIX)  // 7168 tail columns
#define NBLK 512                // persistent blocks (2 per CU; capacity >= 4/CU)
#define TRB 256                 // tail-colsum row blocks (slow path)

typedef float f32x4 __attribute__((ext_vector_type(4)));
typedef int   i32x4 __attribute__((ext_vector_type(4)));
typedef unsigned int u32x4 __attribute__((ext_vector_type(4)));

// ws layout (bytes from start):
// [0]      bar[64]        (unsigned; memset to 0 at graph head each launch)
// then     partial0 [NBLK*PREFIX]   2 MB
//          partial1 [TRB*TAILC]     7 MB
//          prior_eps[N], dope[N], Tprod[PREFIX], colsum_new[N]
//          flag[64], counter[64], worklist[K], nzp[NBLK]  (ints)

__device__ __forceinline__ float fast_tanh_half(float h) {
    // tanh(h/2) = 1 - 2/(e^h + 1)
    float e = __expf(h);
    float r = __builtin_amdgcn_rcpf(e + 1.0f);
    return __builtin_fmaf(-2.0f, r, 1.0f);
}

// clip(2*atanh(P/t), -1, 1) for t != 0, else 0.  2*atanh(P/t)=ln((t+P)/(t-P))
__device__ __forceinline__ float check_msg(float t, float P) {
    float q = (t + P) * __builtin_amdgcn_rcpf(t - P);
    float m = 0.69314718055994531f * __log2f(q);
    m = fminf(fmaxf(m, -1.0f), 1.0f);
    return (t == 0.0f) ? 0.0f : m;
}

// Device-scope grid barrier. Each slot used at most once per launch; the
// graph's leading 256-B memset zeroes all slots every replay (poison-proof).
// All NBLK blocks are co-resident (2/CU vs >=4/CU capacity), so spin is safe.
__device__ __forceinline__ void grid_barrier(unsigned* bar, int slot) {
    __syncthreads();
    if (threadIdx.x == 0) {
        unsigned* cnt = bar + 2 * slot;
        unsigned* gen = bar + 2 * slot + 1;
        __threadfence();
        unsigned g = __hip_atomic_load(gen, __ATOMIC_ACQUIRE, __HIP_MEMORY_SCOPE_AGENT);
        if (__hip_atomic_fetch_add(cnt, 1u, __ATOMIC_ACQ_REL, __HIP_MEMORY_SCOPE_AGENT) == (unsigned)(NBLK - 1)) {
            __hip_atomic_fetch_add(gen, 1u, __ATOMIC_RELEASE, __HIP_MEMORY_SCOPE_AGENT);
        } else {
            while (__hip_atomic_load(gen, __ATOMIC_ACQUIRE, __HIP_MEMORY_SCOPE_AGENT) == g)
                __builtin_amdgcn_s_sleep(2);
        }
        __threadfence();
    }
    __syncthreads();
}

__global__ __launch_bounds__(256, 4) void mega_kernel(
        const float* __restrict__ ps, const float* __restrict__ Min,
        const float* __restrict__ Hxs, const int* __restrict__ x,
        const int* __restrict__ H,
        float* __restrict__ Mout, float* __restrict__ outHxs,
        float* __restrict__ partial0, float* __restrict__ partial1,
        float* __restrict__ prior_eps, float* __restrict__ dope,
        float* __restrict__ Tprod, float* __restrict__ colsum_new,
        int* __restrict__ flag, int* __restrict__ counter,
        int* __restrict__ worklist, int* __restrict__ nzp,
        unsigned* __restrict__ bar) {
    const int b = blockIdx.x;
    const int t = threadIdx.x;
    const int lane = t & 63;

    // ---- Phase A: prefix colsum of Hxs[:, 0:PREFIX] + nonzero detect ----
    {
        const f32x4* p = reinterpret_cast<const f32x4*>(Hxs + (size_t)b * 8 * N_DIM);
        f32x4 acc = {0.f, 0.f, 0.f, 0.f};
        unsigned nz = 0u;
        #pragma unroll
        for (int r = 0; r < 8; ++r) {
            f32x4 v = __builtin_nontemporal_load(&p[(size_t)r * (N_DIM / 4) + t]);
            acc.x += v.x; acc.y += v.y; acc.z += v.z; acc.w += v.w;
            u32x4 u;
            __builtin_memcpy(&u, &v, 16);
            nz |= (u.x | u.y | u.z | u.w);
        }
        reinterpret_cast<f32x4*>(partial0 + (size_t)b * PREFIX)[t] = acc;
        __shared__ int snz;
        if (t == 0) snz = 0;
        __syncthreads();
        if (__any(nz != 0u ? 1 : 0)) {
            if ((t & 63) == 0) atomicOr(&snz, 1);
        }
        __syncthreads();
        if (t == 0) nzp[b] = snz;
    }
    grid_barrier(bar, 0);

    // ---- Phase B: prep (dope all N; prior/Tprod for prefix; flag; counter) ----
    if (b < 32) {
        const int n = b * 256 + t;
        float p0 = ps[2 * n], p1 = ps[2 * n + 1];
        float p1n = p1 / (p0 + p1);
        float dp = logf(1.0f - p1n) - logf(p1n);
        dope[n] = dp;
        colsum_new[n] = 0.0f;
        if (n < PREFIX) {
            float cs = 0.0f;
            #pragma unroll 8
            for (int i = 0; i < NBLK; ++i)
                cs += partial0[(size_t)i * PREFIX + n];
            float m0 = Min[2 * n], m1 = Min[2 * n + 1];
            float m1n = m1 / (m0 + m1);
            float phi = logf(1.0f - m1n) - logf(m1n);
            float prior = dp + phi + cs;
            prior = fminf(fmaxf(prior, -100.0f), 100.0f);
            float pe = prior + 1e-4f;
            prior_eps[n] = pe;
            float T = tanhf(pe * 0.5f);
            Tprod[n] = (T == 0.0f) ? 1.0f : T;
        }
    } else if (b == 32) {
        int v = nzp[t] | nzp[t + 256];
        int any = __any(v != 0 ? 1 : 0) ? 1 : 0;
        __shared__ int w[4];
        if ((t & 63) == 0) w[t >> 6] = any;
        __syncthreads();
        if (t == 0) { flag[0] = (w[0] | w[1] | w[2] | w[3]); counter[0] = 0; }
    }
    grid_barrier(bar, 1);

    // ---- Phase C: per-row prefix product; zero-stream or worklist ----
    {
        const bool fast = (*flag == 0);
        const int wg = b * 4 + (t >> 6);          // 0..2047, 2 rows each
        for (int rr = 0; rr < 2; ++rr) {
            const int k = wg * 2 + rr;
            const i32x4* H4  = reinterpret_cast<const i32x4*>(H + (size_t)k * N_DIM);
            const f32x4* TP4 = reinterpret_cast<const f32x4*>(Tprod);
            const f32x4* PE4 = reinterpret_cast<const f32x4*>(prior_eps);
            const f32x4* HX4 = reinterpret_cast<const f32x4*>(Hxs + (size_t)k * N_DIM);

            float lp0 = 1.f, lp1 = 1.f, lp2 = 1.f, lp3 = 1.f;
            #pragma unroll
            for (int u = 0; u < 4; ++u) {
                const int idx = u * 64 + lane;    // int4 idx 0..255 = cols 0..1023
                const i32x4 hh = H4[idx];
                float f;
                if (fast) {
                    const f32x4 tv = TP4[idx];
                    float f0 = hh.x ? tv.x : 1.f;
                    float f1 = hh.y ? tv.y : 1.f;
                    float f2 = hh.z ? tv.z : 1.f;
                    float f3 = hh.w ? tv.w : 1.f;
                    f = (f0 * f1) * (f2 * f3);
                } else {
                    const f32x4 pe = PE4[idx];
                    const f32x4 hx = HX4[idx];
                    float t0 = fast_tanh_half((hh.x ? pe.x : 0.f) - hx.x);
                    float t1 = fast_tanh_half((hh.y ? pe.y : 0.f) - hx.y);
                    float t2 = fast_tanh_half((hh.z ? pe.z : 0.f) - hx.z);
                    float t3 = fast_tanh_half((hh.w ? pe.w : 0.f) - hx.w);
                    t0 = (t0 == 0.f) ? 1.f : t0;
                    t1 = (t1 == 0.f) ? 1.f : t1;
                    t2 = (t2 == 0.f) ? 1.f : t2;
                    t3 = (t3 == 0.f) ? 1.f : t3;
                    f = (t0 * t1) * (t2 * t3);
                }
                if (u == 0) lp0 *= f;
                if (u == 1) lp1 *= f;
                if (u == 2) lp2 *= f;
                if (u == 3) lp3 *= f;
            }
            float pp = (lp0 * lp1) * (lp2 * lp3);
            #pragma unroll
            for (int off = 1; off < 64; off <<= 1)
                pp *= __shfl_xor(pp, off);

            if (pp == 0.0f) {
                // |t|<=1 monotone: prefix 0 => full product 0 => whole row 0.
                f32x4* orow = reinterpret_cast<f32x4*>(outHxs + (size_t)k * N_DIM);
                const f32x4 z = {0.f, 0.f, 0.f, 0.f};
                #pragma unroll
                for (int s = 0; s < 32; ++s)
                    __builtin_nontemporal_store(z, &orow[s * 64 + lane]);
            } else if (lane == 0) {
                int i = atomicAdd(counter, 1);
                worklist[i] = k;
            }
        }
    }
    grid_barrier(bar, 2);

    const int cnt = *counter;
    if (cnt == 0) {
        // ---- fast-path exit: M_out from colsum_new(=0) + dope ----
        if (b < 32) {
            const int n = b * 256 + t;
            float z = (1.0f - tanhf((colsum_new[n] + dope[n]) * 0.5f)) * 0.5f;
            float2 m; m.x = 1.0f - z; m.y = z;
            reinterpret_cast<float2*>(Mout)[n] = m;
        }
        return;
    }

    // ================= slow path (general inputs) =================
    // Phase E: tail colsum (cols PREFIX:N). Blocks 0..TRB-1, 16 rows each.
    if (b < TRB) {
        const f32x4* p = reinterpret_cast<const f32x4*>(Hxs + (size_t)b * 16 * N_DIM + PREFIX);
        f32x4 acc[7];
        #pragma unroll
        for (int c = 0; c < 7; ++c) acc[c] = (f32x4){0.f, 0.f, 0.f, 0.f};
        for (int r = 0; r < 16; ++r) {
            #pragma unroll
            for (int c = 0; c < 7; ++c) {
                f32x4 v = p[(size_t)r * (N_DIM / 4) + c * 256 + t];
                acc[c].x += v.x; acc[c].y += v.y; acc[c].z += v.z; acc[c].w += v.w;
            }
        }
        f32x4* pr = reinterpret_cast<f32x4*>(partial1 + (size_t)b * TAILC);
        #pragma unroll
        for (int c = 0; c < 7; ++c) pr[c * 256 + t] = acc[c];
    }
    grid_barrier(bar, 3);

    // Phase F: tail prep -> prior_eps for cols PREFIX:N. Blocks 0..27.
    if (b < 28) {
        const int j = b * 256 + t;
        const int n = PREFIX + j;
        float cs = 0.0f;
        #pragma unroll 8
        for (int i = 0; i < TRB; ++i)
            cs += partial1[(size_t)i * TAILC + j];
        float m0 = Min[2 * n], m1 = Min[2 * n + 1];
        float m1n = m1 / (m0 + m1);
        float phi = logf(1.0f - m1n) - logf(m1n);
        float prior = dope[n] + phi + cs;
        prior = fminf(fmaxf(prior, -100.0f), 100.0f);
        prior_eps[n] = prior + 1e-4f;
    }
    grid_barrier(bar, 4);

    // Phase G: fixup worklist rows (full general path).
    {
        const int wg = b * 4 + (t >> 6);
        for (int i = wg; i < cnt; i += NBLK * 4) {
            const int k = worklist[i];
            const i32x4* H4  = reinterpret_cast<const i32x4*>(H + (size_t)k * N_DIM);
            const f32x4* PE4 = reinterpret_cast<const f32x4*>(prior_eps);
            const f32x4* HX4 = reinterpret_cast<const f32x4*>(Hxs + (size_t)k * N_DIM);

            float lp = 1.0f;
            for (int s = 0; s < 32; ++s) {
                const int idx = s * 64 + lane;
                const i32x4 hh = H4[idx];
                const f32x4 pe = PE4[idx];
                const f32x4 hx = HX4[idx];
                float t0 = fast_tanh_half((hh.x ? pe.x : 0.f) - hx.x);
                float t1 = fast_tanh_half((hh.y ? pe.y : 0.f) - hx.y);
                float t2 = fast_tanh_half((hh.z ? pe.z : 0.f) - hx.z);
                float t3 = fast_tanh_half((hh.w ? pe.w : 0.f) - hx.w);
                t0 = (t0 == 0.f) ? 1.f : t0;
                t1 = (t1 == 0.f) ? 1.f : t1;
                t2 = (t2 == 0.f) ? 1.f : t2;
                t3 = (t3 == 0.f) ? 1.f : t3;
                lp *= (t0 * t1) * (t2 * t3);
            }
            #pragma unroll
            for (int off = 1; off < 64; off <<= 1)
                lp *= __shfl_xor(lp, off);

            const float sgn = 1.0f - 2.0f * (float)x[k];
            const float P = sgn * lp;

            f32x4* orow = reinterpret_cast<f32x4*>(outHxs + (size_t)k * N_DIM);
            for (int s = 0; s < 32; ++s) {
                const int idx = s * 64 + lane;
                const i32x4 hh = H4[idx];
                const f32x4 pe = PE4[idx];
                const f32x4 hx = HX4[idx];
                float t0 = fast_tanh_half((hh.x ? pe.x : 0.f) - hx.x);
                float t1 = fast_tanh_half((hh.y ? pe.y : 0.f) - hx.y);
                float t2 = fast_tanh_half((hh.z ? pe.z : 0.f) - hx.z);
                float t3 = fast_tanh_half((hh.w ? pe.w : 0.f) - hx.w);
                f32x4 o;
                o.x = check_msg(t0, P);
                o.y = check_msg(t1, P);
                o.z = check_msg(t2, P);
                o.w = check_msg(t3, P);
                orow[idx] = o;
                const int n0 = idx * 4;
                if (o.x != 0.f) atomicAdd(&colsum_new[n0 + 0], o.x);
                if (o.y != 0.f) atomicAdd(&colsum_new[n0 + 1], o.y);
                if (o.z != 0.f) atomicAdd(&colsum_new[n0 + 2], o.z);
                if (o.w != 0.f) atomicAdd(&colsum_new[n0 + 3], o.w);
            }
        }
    }
    grid_barrier(bar, 5);

    // Phase H: M_out.
    if (b < 32) {
        const int n = b * 256 + t;
        float z = (1.0f - tanhf((colsum_new[n] + dope[n]) * 0.5f)) * 0.5f;
        float2 m; m.x = 1.0f - z; m.y = z;
        reinterpret_cast<float2*>(Mout)[n] = m;
    }
}

extern "C" void kernel_launch(void* const* d_in, const int* in_sizes, int n_in,
                              void* d_out, int out_size, void* d_ws, size_t ws_size,
                              hipStream_t stream) {
    (void)in_sizes; (void)n_in; (void)out_size; (void)ws_size;
    const float* ps  = (const float*)d_in[0];
    const float* Min = (const float*)d_in[1];
    const float* Hxs = (const float*)d_in[2];
    const int*   x   = (const int*)d_in[3];
    const int*   H   = (const int*)d_in[4];

    float* out = (float*)d_out;
    float* Mout = out;                       // N*2 floats
    float* Hxs_new = out + 2 * N_DIM;        // K*N floats

    unsigned* bar     = (unsigned*)d_ws;                      // 64 unsigned
    float* partial0   = (float*)d_ws + 64;                    // NBLK*PREFIX (2 MB)
    float* partial1   = partial0 + (size_t)NBLK * PREFIX;     // TRB*TAILC (7 MB)
    float* prior_eps  = partial1 + (size_t)TRB * TAILC;       // N
    float* dope       = prior_eps + N_DIM;                    // N
    float* Tprod      = dope + N_DIM;                         // PREFIX
    float* colsum_new = Tprod + PREFIX;                       // N
    int*   flag       = (int*)(colsum_new + N_DIM);
    int*   counter    = flag + 64;
    int*   worklist   = counter + 64;                         // K ints
    int*   nzp        = worklist + K_DIM;                     // NBLK ints

    // Poison-proof the grid-barrier state (captured into the graph).
    hipMemsetAsync(bar, 0, 64 * sizeof(unsigned), stream);

    mega_kernel<<<NBLK, 256, 0, stream>>>(ps, Min, Hxs, x, H,
                                          Mout, Hxs_new,
                                          partial0, partial1,
                                          prior_eps, dope, Tprod, colsum_new,
                                          flag, counter, worklist, nzp, bar);
}

// Round 13
// 68.698 us; speedup vs baseline: 5.6306x; 5.6306x over previous
//
#include <hip/hip_runtime.h>

#define K_DIM 4096
#define N_DIM 8192
#define PREFIX 1024             // prefix columns for the underflow test
#define TAILC (N_DIM - PREFIX)  // 7168 tail columns
#define PCB 512                 // prefix-colsum blocks (8 rows each)
#define TRB 256                 // tailfix blocks (slow path; 1/CU co-resident)

typedef float f32x4 __attribute__((ext_vector_type(4)));
typedef int   i32x4 __attribute__((ext_vector_type(4)));
typedef unsigned int u32x4 __attribute__((ext_vector_type(4)));

// ws layout:
// bar[64] (uint, zeroed by prep each launch; used only on slow path)
// partial0 [PCB*PREFIX] (2 MB)
// partial1 [TRB*TAILC]  (7 MB)
// prior_eps[N], dope[N], Tprod[PREFIX], colsum_new[N]
// flag[64], counter[64], worklist[K], nzp[PCB]  (ints)

__device__ __forceinline__ float fast_tanh_half(float h) {
    // tanh(h/2) = 1 - 2/(e^h + 1)
    float e = __expf(h);
    float r = __builtin_amdgcn_rcpf(e + 1.0f);
    return __builtin_fmaf(-2.0f, r, 1.0f);
}

// clip(2*atanh(P/t), -1, 1) for t != 0, else 0.  2*atanh(P/t)=ln((t+P)/(t-P))
__device__ __forceinline__ float check_msg(float t, float P) {
    float q = (t + P) * __builtin_amdgcn_rcpf(t - P);
    float m = 0.69314718055994531f * __log2f(q);
    m = fminf(fmaxf(m, -1.0f), 1.0f);
    return (t == 0.0f) ? 0.0f : m;
}

// Grid barrier for the SLOW PATH ONLY (never executed on the benchmark's fast
// path). TRB=256 blocks = 1 block/CU -> co-resident. Correctness-grade.
__device__ __forceinline__ void grid_barrier(unsigned* bar, int slot, int nblk) {
    __syncthreads();
    if (threadIdx.x == 0) {
        unsigned* cnt = bar + 2 * slot;
        unsigned* gen = bar + 2 * slot + 1;
        __threadfence();
        unsigned g = __hip_atomic_load(gen, __ATOMIC_ACQUIRE, __HIP_MEMORY_SCOPE_AGENT);
        if (__hip_atomic_fetch_add(cnt, 1u, __ATOMIC_ACQ_REL, __HIP_MEMORY_SCOPE_AGENT) == (unsigned)(nblk - 1)) {
            __hip_atomic_fetch_add(gen, 1u, __ATOMIC_RELEASE, __HIP_MEMORY_SCOPE_AGENT);
        } else {
            while (__hip_atomic_load(gen, __ATOMIC_ACQUIRE, __HIP_MEMORY_SCOPE_AGENT) == g)
                __builtin_amdgcn_s_sleep(32);
        }
        __threadfence();
    }
    __syncthreads();
}

// D1: column sums of Hxs[:, 0:PREFIX] + nonzero detect. grid=PCB x 256.
__global__ __launch_bounds__(256) void prefix_colsum_kernel(const float* __restrict__ Hxs,
                                                            float* __restrict__ partial0,
                                                            int* __restrict__ nzp) {
    const int t = threadIdx.x;
    const int b = blockIdx.x;
    const f32x4* p = reinterpret_cast<const f32x4*>(Hxs + (size_t)b * 8 * N_DIM);
    f32x4 acc = {0.f, 0.f, 0.f, 0.f};
    unsigned nz = 0u;
    #pragma unroll
    for (int r = 0; r < 8; ++r) {
        f32x4 v = __builtin_nontemporal_load(&p[(size_t)r * (N_DIM / 4) + t]);
        acc.x += v.x; acc.y += v.y; acc.z += v.z; acc.w += v.w;
        u32x4 u;
        __builtin_memcpy(&u, &v, 16);
        nz |= (u.x | u.y | u.z | u.w);
    }
    reinterpret_cast<f32x4*>(partial0 + (size_t)b * PREFIX)[t] = acc;
    __shared__ int snz;
    if (t == 0) snz = 0;
    __syncthreads();
    if (__any(nz != 0u ? 1 : 0)) {
        if ((t & 63) == 0) atomicOr(&snz, 1);
    }
    __syncthreads();
    if (t == 0) nzp[b] = snz;
}

// D2: prep. grid = 32 x 256 (thread per column n).
// dope all N; colsum_new=0; optimistic Mout = f(dope) (exact on fast path);
// n<PREFIX: prior_eps + Tprod. Block 0: flag, counter, zero bar slots.
__global__ __launch_bounds__(256) void prep_kernel(const float* __restrict__ ps,
                                                   const float* __restrict__ Min,
                                                   const float* __restrict__ partial0,
                                                   const int* __restrict__ nzp,
                                                   float* __restrict__ prior_eps,
                                                   float* __restrict__ dope_out,
                                                   float* __restrict__ Tprod,
                                                   float* __restrict__ colsum_new,
                                                   float* __restrict__ Mout,
                                                   int* __restrict__ flag,
                                                   int* __restrict__ counter,
                                                   unsigned* __restrict__ bar) {
    const int t = threadIdx.x;
    const int n = blockIdx.x * 256 + t;

    float p0 = ps[2 * n], p1 = ps[2 * n + 1];
    float p1n = p1 / (p0 + p1);
    float dp = logf(1.0f - p1n) - logf(p1n);
    dope_out[n] = dp;
    colsum_new[n] = 0.0f;

    // Optimistic output beliefs (colsum_new == 0); tailfix rewrites on slow path.
    {
        float z = (1.0f - tanhf(dp * 0.5f)) * 0.5f;
        float2 m; m.x = 1.0f - z; m.y = z;
        reinterpret_cast<float2*>(Mout)[n] = m;
    }

    if (blockIdx.x == 0) {
        __shared__ int w[4];
        int v = nzp[t] | nzp[t + 256];                  // PCB = 512 entries
        int any = __any(v != 0 ? 1 : 0) ? 1 : 0;
        if ((t & 63) == 0) w[t >> 6] = any;
        __syncthreads();
        if (t == 0) { flag[0] = (w[0] | w[1] | w[2] | w[3]); counter[0] = 0; }
        if (t < 64) bar[t] = 0u;                        // reset slow-path barrier
    }

    if (n < PREFIX) {
        float cs = 0.0f;
        #pragma unroll 8
        for (int i = 0; i < PCB; ++i)
            cs += partial0[(size_t)i * PREFIX + n];
        float m0 = Min[2 * n], m1 = Min[2 * n + 1];
        float m1n = m1 / (m0 + m1);
        float phi = logf(1.0f - m1n) - logf(m1n);
        float prior = dp + phi + cs;
        prior = fminf(fmaxf(prior, -100.0f), 100.0f);
        float pe = prior + 1e-4f;
        prior_eps[n] = pe;
        float T = tanhf(pe * 0.5f);
        Tprod[n] = (T == 0.0f) ? 1.0f : T;
    }
}

// D3: main. ONE WAVE = ONE ROW, no barriers. grid = K/4 x 256.
// Prefix product over cols 0:PREFIX; |t|<=1 => monotone, so prefix==0 => full
// product == 0 => whole row exactly 0 -> nt zero-stream. Else -> worklist.
__global__ __launch_bounds__(256) void main_kernel(const float* __restrict__ Hxs,
                                                   const int* __restrict__ H,
                                                   const float* __restrict__ prior_eps,
                                                   const float* __restrict__ Tprod,
                                                   const int* __restrict__ flag,
                                                   float* __restrict__ out,
                                                   int* __restrict__ counter,
                                                   int* __restrict__ worklist) {
    const int lane = threadIdx.x & 63;
    const int k = blockIdx.x * 4 + (threadIdx.x >> 6);

    const bool fast = (*flag == 0);
    const i32x4* H4  = reinterpret_cast<const i32x4*>(H + (size_t)k * N_DIM);
    const f32x4* TP4 = reinterpret_cast<const f32x4*>(Tprod);
    const f32x4* PE4 = reinterpret_cast<const f32x4*>(prior_eps);
    const f32x4* HX4 = reinterpret_cast<const f32x4*>(Hxs + (size_t)k * N_DIM);

    float lp0 = 1.f, lp1 = 1.f, lp2 = 1.f, lp3 = 1.f;
    #pragma unroll
    for (int u = 0; u < 4; ++u) {
        const int idx = u * 64 + lane;       // int4 idx 0..255 = cols 0..1023
        const i32x4 hh = H4[idx];
        float f;
        if (fast) {
            const f32x4 tv = TP4[idx];
            float f0 = hh.x ? tv.x : 1.f;
            float f1 = hh.y ? tv.y : 1.f;
            float f2 = hh.z ? tv.z : 1.f;
            float f3 = hh.w ? tv.w : 1.f;
            f = (f0 * f1) * (f2 * f3);
        } else {
            const f32x4 pe = PE4[idx];
            const f32x4 hx = HX4[idx];
            float t0 = fast_tanh_half((hh.x ? pe.x : 0.f) - hx.x);
            float t1 = fast_tanh_half((hh.y ? pe.y : 0.f) - hx.y);
            float t2 = fast_tanh_half((hh.z ? pe.z : 0.f) - hx.z);
            float t3 = fast_tanh_half((hh.w ? pe.w : 0.f) - hx.w);
            t0 = (t0 == 0.f) ? 1.f : t0;
            t1 = (t1 == 0.f) ? 1.f : t1;
            t2 = (t2 == 0.f) ? 1.f : t2;
            t3 = (t3 == 0.f) ? 1.f : t3;
            f = (t0 * t1) * (t2 * t3);
        }
        if (u == 0) lp0 *= f;
        if (u == 1) lp1 *= f;
        if (u == 2) lp2 *= f;
        if (u == 3) lp3 *= f;
    }
    float pp = (lp0 * lp1) * (lp2 * lp3);
    #pragma unroll
    for (int off = 1; off < 64; off <<= 1)
        pp *= __shfl_xor(pp, off);

    if (pp == 0.0f) {
        f32x4* orow = reinterpret_cast<f32x4*>(out + (size_t)k * N_DIM);
        const f32x4 z = {0.f, 0.f, 0.f, 0.f};
        #pragma unroll
        for (int s = 0; s < 32; ++s)
            __builtin_nontemporal_store(z, &orow[s * 64 + lane]);
    } else if (lane == 0) {
        int i = atomicAdd(counter, 1);
        worklist[i] = k;
    }
}

// D4: tailfix -- early-exit on fast path; full general path otherwise.
// grid = TRB x 256 (1 block/CU -> co-resident; barrier is slow-path-only).
__global__ __launch_bounds__(256) void tailfix_kernel(const float* __restrict__ Hxs,
                                                      const int* __restrict__ H,
                                                      const int* __restrict__ x,
                                                      const float* __restrict__ Min,
                                                      const float* __restrict__ dope,
                                                      float* __restrict__ prior_eps,
                                                      float* __restrict__ partial1,
                                                      float* __restrict__ colsum_new,
                                                      const int* __restrict__ counter,
                                                      const int* __restrict__ worklist,
                                                      float* __restrict__ out,
                                                      float* __restrict__ Mout,
                                                      unsigned* __restrict__ bar) {
    const int cnt = *counter;
    if (cnt == 0) return;                    // fast path: optimistic Mout stands

    const int b = blockIdx.x;
    const int t = threadIdx.x;
    const int lane = t & 63;

    // E: tail colsum (cols PREFIX:N), 16 rows per block.
    {
        const f32x4* p = reinterpret_cast<const f32x4*>(Hxs + (size_t)b * 16 * N_DIM + PREFIX);
        f32x4 acc[7];
        #pragma unroll
        for (int c = 0; c < 7; ++c) acc[c] = (f32x4){0.f, 0.f, 0.f, 0.f};
        for (int r = 0; r < 16; ++r) {
            #pragma unroll
            for (int c = 0; c < 7; ++c) {
                f32x4 v = p[(size_t)r * (N_DIM / 4) + c * 256 + t];
                acc[c].x += v.x; acc[c].y += v.y; acc[c].z += v.z; acc[c].w += v.w;
            }
        }
        f32x4* pr = reinterpret_cast<f32x4*>(partial1 + (size_t)b * TAILC);
        #pragma unroll
        for (int c = 0; c < 7; ++c) pr[c * 256 + t] = acc[c];
    }
    grid_barrier(bar, 0, TRB);

    // F: tail prep -> prior_eps for cols PREFIX:N (28*256 = 7168 threads).
    if (b < 28) {
        const int j = b * 256 + t;
        const int n = PREFIX + j;
        float cs = 0.0f;
        #pragma unroll 8
        for (int i = 0; i < TRB; ++i)
            cs += partial1[(size_t)i * TAILC + j];
        float m0 = Min[2 * n], m1 = Min[2 * n + 1];
        float m1n = m1 / (m0 + m1);
        float phi = logf(1.0f - m1n) - logf(m1n);
        float prior = dope[n] + phi + cs;
        prior = fminf(fmaxf(prior, -100.0f), 100.0f);
        prior_eps[n] = prior + 1e-4f;
    }
    grid_barrier(bar, 1, TRB);

    // G: fixup worklist rows (full general path).
    {
        const int wg = b * 4 + (t >> 6);
        for (int i = wg; i < cnt; i += TRB * 4) {
            const int k = worklist[i];
            const i32x4* H4  = reinterpret_cast<const i32x4*>(H + (size_t)k * N_DIM);
            const f32x4* PE4 = reinterpret_cast<const f32x4*>(prior_eps);
            const f32x4* HX4 = reinterpret_cast<const f32x4*>(Hxs + (size_t)k * N_DIM);

            float lp = 1.0f;
            for (int s = 0; s < 32; ++s) {
                const int idx = s * 64 + lane;
                const i32x4 hh = H4[idx];
                const f32x4 pe = PE4[idx];
                const f32x4 hx = HX4[idx];
                float t0 = fast_tanh_half((hh.x ? pe.x : 0.f) - hx.x);
                float t1 = fast_tanh_half((hh.y ? pe.y : 0.f) - hx.y);
                float t2 = fast_tanh_half((hh.z ? pe.z : 0.f) - hx.z);
                float t3 = fast_tanh_half((hh.w ? pe.w : 0.f) - hx.w);
                t0 = (t0 == 0.f) ? 1.f : t0;
                t1 = (t1 == 0.f) ? 1.f : t1;
                t2 = (t2 == 0.f) ? 1.f : t2;
                t3 = (t3 == 0.f) ? 1.f : t3;
                lp *= (t0 * t1) * (t2 * t3);
            }
            #pragma unroll
            for (int off = 1; off < 64; off <<= 1)
                lp *= __shfl_xor(lp, off);

            const float sgn = 1.0f - 2.0f * (float)x[k];
            const float P = sgn * lp;

            f32x4* orow = reinterpret_cast<f32x4*>(out + (size_t)k * N_DIM);
            for (int s = 0; s < 32; ++s) {
                const int idx = s * 64 + lane;
                const i32x4 hh = H4[idx];
                const f32x4 pe = PE4[idx];
                const f32x4 hx = HX4[idx];
                float t0 = fast_tanh_half((hh.x ? pe.x : 0.f) - hx.x);
                float t1 = fast_tanh_half((hh.y ? pe.y : 0.f) - hx.y);
                float t2 = fast_tanh_half((hh.z ? pe.z : 0.f) - hx.z);
                float t3 = fast_tanh_half((hh.w ? pe.w : 0.f) - hx.w);
                f32x4 o;
                o.x = check_msg(t0, P);
                o.y = check_msg(t1, P);
                o.z = check_msg(t2, P);
                o.w = check_msg(t3, P);
                orow[idx] = o;
                const int n0 = idx * 4;
                if (o.x != 0.f) atomicAdd(&colsum_new[n0 + 0], o.x);
                if (o.y != 0.f) atomicAdd(&colsum_new[n0 + 1], o.y);
                if (o.z != 0.f) atomicAdd(&colsum_new[n0 + 2], o.z);
                if (o.w != 0.f) atomicAdd(&colsum_new[n0 + 3], o.w);
            }
        }
    }
    grid_barrier(bar, 2, TRB);

    // H: rewrite Mout with the true colsum_new.
    if (b < 32) {
        const int n = b * 256 + t;
        float z = (1.0f - tanhf((colsum_new[n] + dope[n]) * 0.5f)) * 0.5f;
        float2 m; m.x = 1.0f - z; m.y = z;
        reinterpret_cast<float2*>(Mout)[n] = m;
    }
}

extern "C" void kernel_launch(void* const* d_in, const int* in_sizes, int n_in,
                              void* d_out, int out_size, void* d_ws, size_t ws_size,
                              hipStream_t stream) {
    (void)in_sizes; (void)n_in; (void)out_size; (void)ws_size;
    const float* ps  = (const float*)d_in[0];
    const float* Min = (const float*)d_in[1];
    const float* Hxs = (const float*)d_in[2];
    const int*   x   = (const int*)d_in[3];
    const int*   H   = (const int*)d_in[4];

    float* out = (float*)d_out;
    float* Mout = out;                       // N*2 floats
    float* Hxs_new = out + 2 * N_DIM;        // K*N floats

    unsigned* bar     = (unsigned*)d_ws;                      // 64 uints
    float* partial0   = (float*)d_ws + 64;                    // PCB*PREFIX (2 MB)
    float* partial1   = partial0 + (size_t)PCB * PREFIX;      // TRB*TAILC (7 MB)
    float* prior_eps  = partial1 + (size_t)TRB * TAILC;       // N
    float* dope       = prior_eps + N_DIM;                    // N
    float* Tprod      = dope + N_DIM;                         // PREFIX
    float* colsum_new = Tprod + PREFIX;                       // N
    int*   flag       = (int*)(colsum_new + N_DIM);
    int*   counter    = flag + 64;
    int*   worklist   = counter + 64;                         // K ints
    int*   nzp        = worklist + K_DIM;                     // PCB ints

    prefix_colsum_kernel<<<PCB, 256, 0, stream>>>(Hxs, partial0, nzp);

    prep_kernel<<<N_DIM / 256, 256, 0, stream>>>(ps, Min, partial0, nzp,
                                                 prior_eps, dope, Tprod,
                                                 colsum_new, Mout, flag,
                                                 counter, bar);

    main_kernel<<<K_DIM / 4, 256, 0, stream>>>(Hxs, H, prior_eps, Tprod, flag,
                                               Hxs_new, counter, worklist);

    tailfix_kernel<<<TRB, 256, 0, stream>>>(Hxs, H, x, Min, dope, prior_eps,
                                            partial1, colsum_new, counter,
                                            worklist, Hxs_new, Mout, bar);
}

// Round 14
// 50.939 us; speedup vs baseline: 7.5935x; 1.3486x over previous
//
#include <hip/hip_runtime.h>

#define K_DIM 4096
#define N_DIM 8192
#define PREFIX 1024             // prefix columns for the underflow test
#define TAILC (N_DIM - PREFIX)  // 7168 tail columns
#define PCB 256                 // prefix-colsum blocks (16 rows each)
#define TRB 256                 // tailfix blocks (slow path; 1/CU co-resident)

typedef float f32x4 __attribute__((ext_vector_type(4)));
typedef int   i32x4 __attribute__((ext_vector_type(4)));
typedef unsigned int u32x4 __attribute__((ext_vector_type(4)));

// ws layout:
// bar[64] (uint, zeroed by prep each launch; used only on slow path)
// partial0 [PCB*PREFIX] (1 MB)
// partial1 [TRB*TAILC]  (7 MB)
// prior_eps[N], dope[N], Tprod[PREFIX], colsum_new[N]
// flag[64], counter[64], worklist[K], nzp[PCB]  (ints)

__device__ __forceinline__ float fast_tanh_half(float h) {
    // tanh(h/2) = 1 - 2/(e^h + 1)
    float e = __expf(h);
    float r = __builtin_amdgcn_rcpf(e + 1.0f);
    return __builtin_fmaf(-2.0f, r, 1.0f);
}

// clip(2*atanh(P/t), -1, 1) for t != 0, else 0.  2*atanh(P/t)=ln((t+P)/(t-P))
__device__ __forceinline__ float check_msg(float t, float P) {
    float q = (t + P) * __builtin_amdgcn_rcpf(t - P);
    float m = 0.69314718055994531f * __log2f(q);
    m = fminf(fmaxf(m, -1.0f), 1.0f);
    return (t == 0.0f) ? 0.0f : m;
}

// Grid barrier for the SLOW PATH ONLY (never executed on the fast path).
// TRB=256 blocks = 1 block/CU -> co-resident. Correctness-grade, not fast.
__device__ __forceinline__ void grid_barrier(unsigned* bar, int slot, int nblk) {
    __syncthreads();
    if (threadIdx.x == 0) {
        unsigned* cnt = bar + 2 * slot;
        unsigned* gen = bar + 2 * slot + 1;
        __threadfence();
        unsigned g = __hip_atomic_load(gen, __ATOMIC_ACQUIRE, __HIP_MEMORY_SCOPE_AGENT);
        if (__hip_atomic_fetch_add(cnt, 1u, __ATOMIC_ACQ_REL, __HIP_MEMORY_SCOPE_AGENT) == (unsigned)(nblk - 1)) {
            __hip_atomic_fetch_add(gen, 1u, __ATOMIC_RELEASE, __HIP_MEMORY_SCOPE_AGENT);
        } else {
            while (__hip_atomic_load(gen, __ATOMIC_ACQUIRE, __HIP_MEMORY_SCOPE_AGENT) == g)
                __builtin_amdgcn_s_sleep(32);
        }
        __threadfence();
    }
    __syncthreads();
}

// D2: column sums of Hxs[:, 0:PREFIX] + nonzero detect. grid=PCB x 256.
// Block b: rows [16b, 16b+16); thread t covers cols 4t..4t+3.
__global__ __launch_bounds__(256) void prefix_colsum_kernel(const float* __restrict__ Hxs,
                                                            float* __restrict__ partial0,
                                                            int* __restrict__ nzp) {
    const int t = threadIdx.x;
    const int b = blockIdx.x;
    const f32x4* p = reinterpret_cast<const f32x4*>(Hxs + (size_t)b * 16 * N_DIM);
    f32x4 acc = {0.f, 0.f, 0.f, 0.f};
    unsigned nz = 0u;
    #pragma unroll
    for (int r = 0; r < 16; ++r) {
        f32x4 v = __builtin_nontemporal_load(&p[(size_t)r * (N_DIM / 4) + t]);
        acc.x += v.x; acc.y += v.y; acc.z += v.z; acc.w += v.w;
        u32x4 u;
        __builtin_memcpy(&u, &v, 16);
        nz |= (u.x | u.y | u.z | u.w);
    }
    reinterpret_cast<f32x4*>(partial0 + (size_t)b * PREFIX)[t] = acc;
    __shared__ int snz;
    if (t == 0) snz = 0;
    __syncthreads();
    if (__any(nz != 0u ? 1 : 0)) {
        if ((t & 63) == 0) atomicOr(&snz, 1);
    }
    __syncthreads();
    if (t == 0) nzp[b] = snz;
}

// D3: prep. grid = 32 x 256 (thread per column n).
// dope all N; colsum_new=0; optimistic Mout = f(dope) (exact on fast path);
// n<PREFIX: prior_eps + Tprod. Block 0: flag, counter, zero bar slots.
__global__ __launch_bounds__(256) void prep_kernel(const float* __restrict__ ps,
                                                   const float* __restrict__ Min,
                                                   const float* __restrict__ partial0,
                                                   const int* __restrict__ nzp,
                                                   float* __restrict__ prior_eps,
                                                   float* __restrict__ dope_out,
                                                   float* __restrict__ Tprod,
                                                   float* __restrict__ colsum_new,
                                                   float* __restrict__ Mout,
                                                   int* __restrict__ flag,
                                                   int* __restrict__ counter,
                                                   unsigned* __restrict__ bar) {
    const int t = threadIdx.x;
    const int n = blockIdx.x * 256 + t;

    float p0 = ps[2 * n], p1 = ps[2 * n + 1];
    float p1n = p1 / (p0 + p1);
    float dp = logf(1.0f - p1n) - logf(p1n);
    dope_out[n] = dp;
    colsum_new[n] = 0.0f;

    // Optimistic output beliefs (colsum_new == 0); tailfix rewrites on slow path.
    {
        float z = (1.0f - tanhf(dp * 0.5f)) * 0.5f;
        float2 m; m.x = 1.0f - z; m.y = z;
        reinterpret_cast<float2*>(Mout)[n] = m;
    }

    if (blockIdx.x == 0) {
        __shared__ int w[4];
        int v = nzp[t];                                 // PCB = 256 entries
        int any = __any(v != 0 ? 1 : 0) ? 1 : 0;
        if ((t & 63) == 0) w[t >> 6] = any;
        __syncthreads();
        if (t == 0) { flag[0] = (w[0] | w[1] | w[2] | w[3]); counter[0] = 0; }
        if (t < 64) bar[t] = 0u;                        // reset slow-path barrier
    }

    if (n < PREFIX) {
        float cs = 0.0f;
        #pragma unroll 8
        for (int i = 0; i < PCB; ++i)
            cs += partial0[(size_t)i * PREFIX + n];
        float m0 = Min[2 * n], m1 = Min[2 * n + 1];
        float m1n = m1 / (m0 + m1);
        float phi = logf(1.0f - m1n) - logf(m1n);
        float prior = dp + phi + cs;
        prior = fminf(fmaxf(prior, -100.0f), 100.0f);
        float pe = prior + 1e-4f;
        prior_eps[n] = pe;
        float T = tanhf(pe * 0.5f);
        Tprod[n] = (T == 0.0f) ? 1.0f : T;
    }
}

// D4: main -- COMPUTE ONLY (no stores; memset already zeroed the output).
// ONE WAVE = ONE ROW. grid = K/4 x 256. Prefix product over cols 0:PREFIX;
// |t|<=1 => monotone, so prefix==0 => full product 0 => whole row stays the
// memset zeros. Nonzero prefix -> worklist for tailfix.
__global__ __launch_bounds__(256) void main_kernel(const float* __restrict__ Hxs,
                                                   const int* __restrict__ H,
                                                   const float* __restrict__ prior_eps,
                                                   const float* __restrict__ Tprod,
                                                   const int* __restrict__ flag,
                                                   int* __restrict__ counter,
                                                   int* __restrict__ worklist) {
    const int lane = threadIdx.x & 63;
    const int k = blockIdx.x * 4 + (threadIdx.x >> 6);

    const bool fast = (*flag == 0);
    const i32x4* H4  = reinterpret_cast<const i32x4*>(H + (size_t)k * N_DIM);
    const f32x4* TP4 = reinterpret_cast<const f32x4*>(Tprod);
    const f32x4* PE4 = reinterpret_cast<const f32x4*>(prior_eps);
    const f32x4* HX4 = reinterpret_cast<const f32x4*>(Hxs + (size_t)k * N_DIM);

    float lp0 = 1.f, lp1 = 1.f, lp2 = 1.f, lp3 = 1.f;
    #pragma unroll
    for (int u = 0; u < 4; ++u) {
        const int idx = u * 64 + lane;       // int4 idx 0..255 = cols 0..1023
        const i32x4 hh = __builtin_nontemporal_load(&H4[idx]);
        float f;
        if (fast) {
            const f32x4 tv = TP4[idx];
            float f0 = hh.x ? tv.x : 1.f;
            float f1 = hh.y ? tv.y : 1.f;
            float f2 = hh.z ? tv.z : 1.f;
            float f3 = hh.w ? tv.w : 1.f;
            f = (f0 * f1) * (f2 * f3);
        } else {
            const f32x4 pe = PE4[idx];
            const f32x4 hx = HX4[idx];
            float t0 = fast_tanh_half((hh.x ? pe.x : 0.f) - hx.x);
            float t1 = fast_tanh_half((hh.y ? pe.y : 0.f) - hx.y);
            float t2 = fast_tanh_half((hh.z ? pe.z : 0.f) - hx.z);
            float t3 = fast_tanh_half((hh.w ? pe.w : 0.f) - hx.w);
            t0 = (t0 == 0.f) ? 1.f : t0;
            t1 = (t1 == 0.f) ? 1.f : t1;
            t2 = (t2 == 0.f) ? 1.f : t2;
            t3 = (t3 == 0.f) ? 1.f : t3;
            f = (t0 * t1) * (t2 * t3);
        }
        if (u == 0) lp0 *= f;
        if (u == 1) lp1 *= f;
        if (u == 2) lp2 *= f;
        if (u == 3) lp3 *= f;
    }
    float pp = (lp0 * lp1) * (lp2 * lp3);
    #pragma unroll
    for (int off = 1; off < 64; off <<= 1)
        pp *= __shfl_xor(pp, off);

    if (pp != 0.0f && lane == 0) {
        int i = atomicAdd(counter, 1);
        worklist[i] = k;
    }
}

// D5: tailfix -- early-exit on fast path; full general path otherwise.
// grid = TRB x 256 (1 block/CU -> co-resident; barrier is slow-path-only).
__global__ __launch_bounds__(256) void tailfix_kernel(const float* __restrict__ Hxs,
                                                      const int* __restrict__ H,
                                                      const int* __restrict__ x,
                                                      const float* __restrict__ Min,
                                                      const float* __restrict__ dope,
                                                      float* __restrict__ prior_eps,
                                                      float* __restrict__ partial1,
                                                      float* __restrict__ colsum_new,
                                                      const int* __restrict__ counter,
                                                      const int* __restrict__ worklist,
                                                      float* __restrict__ out,
                                                      float* __restrict__ Mout,
                                                      unsigned* __restrict__ bar) {
    const int cnt = *counter;
    if (cnt == 0) return;                    // fast path: memset zeros + optimistic Mout stand

    const int b = blockIdx.x;
    const int t = threadIdx.x;
    const int lane = t & 63;

    // E: tail colsum (cols PREFIX:N), 16 rows per block.
    {
        const f32x4* p = reinterpret_cast<const f32x4*>(Hxs + (size_t)b * 16 * N_DIM + PREFIX);
        f32x4 acc[7];
        #pragma unroll
        for (int c = 0; c < 7; ++c) acc[c] = (f32x4){0.f, 0.f, 0.f, 0.f};
        for (int r = 0; r < 16; ++r) {
            #pragma unroll
            for (int c = 0; c < 7; ++c) {
                f32x4 v = p[(size_t)r * (N_DIM / 4) + c * 256 + t];
                acc[c].x += v.x; acc[c].y += v.y; acc[c].z += v.z; acc[c].w += v.w;
            }
        }
        f32x4* pr = reinterpret_cast<f32x4*>(partial1 + (size_t)b * TAILC);
        #pragma unroll
        for (int c = 0; c < 7; ++c) pr[c * 256 + t] = acc[c];
    }
    grid_barrier(bar, 0, TRB);

    // F: tail prep -> prior_eps for cols PREFIX:N (28*256 = 7168 threads).
    if (b < 28) {
        const int j = b * 256 + t;
        const int n = PREFIX + j;
        float cs = 0.0f;
        #pragma unroll 8
        for (int i = 0; i < TRB; ++i)
            cs += partial1[(size_t)i * TAILC + j];
        float m0 = Min[2 * n], m1 = Min[2 * n + 1];
        float m1n = m1 / (m0 + m1);
        float phi = logf(1.0f - m1n) - logf(m1n);
        float prior = dope[n] + phi + cs;
        prior = fminf(fmaxf(prior, -100.0f), 100.0f);
        prior_eps[n] = prior + 1e-4f;
    }
    grid_barrier(bar, 1, TRB);

    // G: fixup worklist rows (full general path; overwrites memset zeros).
    {
        const int wg = b * 4 + (t >> 6);
        for (int i = wg; i < cnt; i += TRB * 4) {
            const int k = worklist[i];
            const i32x4* H4  = reinterpret_cast<const i32x4*>(H + (size_t)k * N_DIM);
            const f32x4* PE4 = reinterpret_cast<const f32x4*>(prior_eps);
            const f32x4* HX4 = reinterpret_cast<const f32x4*>(Hxs + (size_t)k * N_DIM);

            float lp = 1.0f;
            for (int s = 0; s < 32; ++s) {
                const int idx = s * 64 + lane;
                const i32x4 hh = H4[idx];
                const f32x4 pe = PE4[idx];
                const f32x4 hx = HX4[idx];
                float t0 = fast_tanh_half((hh.x ? pe.x : 0.f) - hx.x);
                float t1 = fast_tanh_half((hh.y ? pe.y : 0.f) - hx.y);
                float t2 = fast_tanh_half((hh.z ? pe.z : 0.f) - hx.z);
                float t3 = fast_tanh_half((hh.w ? pe.w : 0.f) - hx.w);
                t0 = (t0 == 0.f) ? 1.f : t0;
                t1 = (t1 == 0.f) ? 1.f : t1;
                t2 = (t2 == 0.f) ? 1.f : t2;
                t3 = (t3 == 0.f) ? 1.f : t3;
                lp *= (t0 * t1) * (t2 * t3);
            }
            #pragma unroll
            for (int off = 1; off < 64; off <<= 1)
                lp *= __shfl_xor(lp, off);

            const float sgn = 1.0f - 2.0f * (float)x[k];
            const float P = sgn * lp;

            f32x4* orow = reinterpret_cast<f32x4*>(out + (size_t)k * N_DIM);
            for (int s = 0; s < 32; ++s) {
                const int idx = s * 64 + lane;
                const i32x4 hh = H4[idx];
                const f32x4 pe = PE4[idx];
                const f32x4 hx = HX4[idx];
                float t0 = fast_tanh_half((hh.x ? pe.x : 0.f) - hx.x);
                float t1 = fast_tanh_half((hh.y ? pe.y : 0.f) - hx.y);
                float t2 = fast_tanh_half((hh.z ? pe.z : 0.f) - hx.z);
                float t3 = fast_tanh_half((hh.w ? pe.w : 0.f) - hx.w);
                f32x4 o;
                o.x = check_msg(t0, P);
                o.y = check_msg(t1, P);
                o.z = check_msg(t2, P);
                o.w = check_msg(t3, P);
                orow[idx] = o;
                const int n0 = idx * 4;
                if (o.x != 0.f) atomicAdd(&colsum_new[n0 + 0], o.x);
                if (o.y != 0.f) atomicAdd(&colsum_new[n0 + 1], o.y);
                if (o.z != 0.f) atomicAdd(&colsum_new[n0 + 2], o.z);
                if (o.w != 0.f) atomicAdd(&colsum_new[n0 + 3], o.w);
            }
        }
    }
    grid_barrier(bar, 2, TRB);

    // H: rewrite Mout with the true colsum_new.
    if (b < 32) {
        const int n = b * 256 + t;
        float z = (1.0f - tanhf((colsum_new[n] + dope[n]) * 0.5f)) * 0.5f;
        float2 m; m.x = 1.0f - z; m.y = z;
        reinterpret_cast<float2*>(Mout)[n] = m;
    }
}

extern "C" void kernel_launch(void* const* d_in, const int* in_sizes, int n_in,
                              void* d_out, int out_size, void* d_ws, size_t ws_size,
                              hipStream_t stream) {
    (void)in_sizes; (void)n_in; (void)out_size; (void)ws_size;
    const float* ps  = (const float*)d_in[0];
    const float* Min = (const float*)d_in[1];
    const float* Hxs = (const float*)d_in[2];
    const int*   x   = (const int*)d_in[3];
    const int*   H   = (const int*)d_in[4];

    float* out = (float*)d_out;
    float* Mout = out;                       // N*2 floats
    float* Hxs_new = out + 2 * N_DIM;        // K*N floats

    unsigned* bar     = (unsigned*)d_ws;                      // 64 uints
    float* partial0   = (float*)d_ws + 64;                    // PCB*PREFIX (1 MB)
    float* partial1   = partial0 + (size_t)PCB * PREFIX;      // TRB*TAILC (7 MB)
    float* prior_eps  = partial1 + (size_t)TRB * TAILC;       // N
    float* dope       = prior_eps + N_DIM;                    // N
    float* Tprod      = dope + N_DIM;                         // PREFIX
    float* colsum_new = Tprod + PREFIX;                       // N
    int*   flag       = (int*)(colsum_new + N_DIM);
    int*   counter    = flag + 64;
    int*   worklist   = counter + 64;                         // K ints
    int*   nzp        = worklist + K_DIM;                     // PCB ints

    // D1: zero the big output via the runtime fill kernel (~7.2 TB/s).
    // On the fast path this IS Hxs_new; tailfix overwrites worklist rows.
    hipMemsetAsync(Hxs_new, 0, (size_t)K_DIM * N_DIM * sizeof(float), stream);

    prefix_colsum_kernel<<<PCB, 256, 0, stream>>>(Hxs, partial0, nzp);

    prep_kernel<<<N_DIM / 256, 256, 0, stream>>>(ps, Min, partial0, nzp,
                                                 prior_eps, dope, Tprod,
                                                 colsum_new, Mout, flag,
                                                 counter, bar);

    main_kernel<<<K_DIM / 4, 256, 0, stream>>>(Hxs, H, prior_eps, Tprod, flag,
                                               counter, worklist);

    tailfix_kernel<<<TRB, 256, 0, stream>>>(Hxs, H, x, Min, dope, prior_eps,
                                            partial1, colsum_new, counter,
                                            worklist, Hxs_new, Mout, bar);
}

// Round 15
// 47.059 us; speedup vs baseline: 8.2196x; 1.0825x over previous
//
#include <hip/hip_runtime.h>

#define K_DIM 4096
#define N_DIM 8192
#define PREFIX 1024             // prefix columns for the underflow test
#define TAILC (N_DIM - PREFIX)  // 7168 tail columns
#define PCB 256                 // prefix-colsum blocks (16 rows each)
#define TRB 256                 // tailfix blocks (slow path; 1/CU co-resident)

typedef float f32x4 __attribute__((ext_vector_type(4)));
typedef int   i32x4 __attribute__((ext_vector_type(4)));
typedef unsigned int u32x4 __attribute__((ext_vector_type(4)));

// ws layout:
// bar[64] (uint, zeroed by prep each launch; used only on slow path)
// partial0 [PCB*PREFIX] (1 MB)
// partial1 [TRB*TAILC]  (7 MB)
// prior_eps[N], dope[N], Tprod[PREFIX], colsum_new[N]
// flag[64], counter[64], worklist[K], nzp[PCB]  (ints)

__device__ __forceinline__ float fast_tanh_half(float h) {
    // tanh(h/2) = 1 - 2/(e^h + 1)
    float e = __expf(h);
    float r = __builtin_amdgcn_rcpf(e + 1.0f);
    return __builtin_fmaf(-2.0f, r, 1.0f);
}

// clip(2*atanh(P/t), -1, 1) for t != 0, else 0.  2*atanh(P/t)=ln((t+P)/(t-P))
__device__ __forceinline__ float check_msg(float t, float P) {
    float q = (t + P) * __builtin_amdgcn_rcpf(t - P);
    float m = 0.69314718055994531f * __log2f(q);
    m = fminf(fmaxf(m, -1.0f), 1.0f);
    return (t == 0.0f) ? 0.0f : m;
}

// Grid barrier for the SLOW PATH ONLY (never executed on the fast path).
// TRB=256 blocks = 1 block/CU -> co-resident. Correctness-grade, not fast.
__device__ __forceinline__ void grid_barrier(unsigned* bar, int slot, int nblk) {
    __syncthreads();
    if (threadIdx.x == 0) {
        unsigned* cnt = bar + 2 * slot;
        unsigned* gen = bar + 2 * slot + 1;
        __threadfence();
        unsigned g = __hip_atomic_load(gen, __ATOMIC_ACQUIRE, __HIP_MEMORY_SCOPE_AGENT);
        if (__hip_atomic_fetch_add(cnt, 1u, __ATOMIC_ACQ_REL, __HIP_MEMORY_SCOPE_AGENT) == (unsigned)(nblk - 1)) {
            __hip_atomic_fetch_add(gen, 1u, __ATOMIC_RELEASE, __HIP_MEMORY_SCOPE_AGENT);
        } else {
            while (__hip_atomic_load(gen, __ATOMIC_ACQUIRE, __HIP_MEMORY_SCOPE_AGENT) == g)
                __builtin_amdgcn_s_sleep(32);
        }
        __threadfence();
    }
    __syncthreads();
}

// D1: column sums of Hxs[:, 0:PREFIX] + nonzero detect. grid=PCB x 256.
__global__ __launch_bounds__(256) void prefix_colsum_kernel(const float* __restrict__ Hxs,
                                                            float* __restrict__ partial0,
                                                            int* __restrict__ nzp) {
    const int t = threadIdx.x;
    const int b = blockIdx.x;
    const f32x4* p = reinterpret_cast<const f32x4*>(Hxs + (size_t)b * 16 * N_DIM);
    f32x4 acc = {0.f, 0.f, 0.f, 0.f};
    unsigned nz = 0u;
    #pragma unroll
    for (int r = 0; r < 16; ++r) {
        f32x4 v = __builtin_nontemporal_load(&p[(size_t)r * (N_DIM / 4) + t]);
        acc.x += v.x; acc.y += v.y; acc.z += v.z; acc.w += v.w;
        u32x4 u;
        __builtin_memcpy(&u, &v, 16);
        nz |= (u.x | u.y | u.z | u.w);
    }
    reinterpret_cast<f32x4*>(partial0 + (size_t)b * PREFIX)[t] = acc;
    __shared__ int snz;
    if (t == 0) snz = 0;
    __syncthreads();
    if (__any(nz != 0u ? 1 : 0)) {
        if ((t & 63) == 0) atomicOr(&snz, 1);
    }
    __syncthreads();
    if (t == 0) nzp[b] = snz;
}

// D2: prep. grid = 32 x 256 (thread per column n).
__global__ __launch_bounds__(256) void prep_kernel(const float* __restrict__ ps,
                                                   const float* __restrict__ Min,
                                                   const float* __restrict__ partial0,
                                                   const int* __restrict__ nzp,
                                                   float* __restrict__ prior_eps,
                                                   float* __restrict__ dope_out,
                                                   float* __restrict__ Tprod,
                                                   float* __restrict__ colsum_new,
                                                   float* __restrict__ Mout,
                                                   int* __restrict__ flag,
                                                   int* __restrict__ counter,
                                                   unsigned* __restrict__ bar) {
    const int t = threadIdx.x;
    const int n = blockIdx.x * 256 + t;

    float p0 = ps[2 * n], p1 = ps[2 * n + 1];
    float p1n = p1 / (p0 + p1);
    float dp = logf(1.0f - p1n) - logf(p1n);
    dope_out[n] = dp;
    colsum_new[n] = 0.0f;

    // Optimistic output beliefs (colsum_new == 0); tailfix rewrites on slow path.
    {
        float z = (1.0f - tanhf(dp * 0.5f)) * 0.5f;
        float2 m; m.x = 1.0f - z; m.y = z;
        reinterpret_cast<float2*>(Mout)[n] = m;
    }

    if (blockIdx.x == 0) {
        __shared__ int w[4];
        int v = nzp[t];                                 // PCB = 256 entries
        int any = __any(v != 0 ? 1 : 0) ? 1 : 0;
        if ((t & 63) == 0) w[t >> 6] = any;
        __syncthreads();
        if (t == 0) { flag[0] = (w[0] | w[1] | w[2] | w[3]); counter[0] = 0; }
        if (t < 64) bar[t] = 0u;                        // reset slow-path barrier
    }

    if (n < PREFIX) {
        float cs = 0.0f;
        #pragma unroll 8
        for (int i = 0; i < PCB; ++i)
            cs += partial0[(size_t)i * PREFIX + n];
        float m0 = Min[2 * n], m1 = Min[2 * n + 1];
        float m1n = m1 / (m0 + m1);
        float phi = logf(1.0f - m1n) - logf(m1n);
        float prior = dp + phi + cs;
        prior = fminf(fmaxf(prior, -100.0f), 100.0f);
        float pe = prior + 1e-4f;
        prior_eps[n] = pe;
        float T = tanhf(pe * 0.5f);
        Tprod[n] = (T == 0.0f) ? 1.0f : T;
    }
}

// D3: mainfill -- fused prefix-test + zero-fill, full occupancy, PLAIN stores.
// grid = 2048 x 256 (8 blocks/CU, 32 waves/CU). Block b: rows 2b, 2b+1.
// Waves (w>>1) pick the row; w&1 picks the half. Per wave: 2 H-int4 prefix
// loads (512 cols), product, butterfly; halves combine via 4-float LDS + ONE
// barrier. pp==0 (common: |t|<=1 monotone product underflow) -> stream the
// 16KB half-row of zeros (plain stores through L2). Else -> worklist; row is
// written entirely by tailfix's fixup, so no pre-zeroing is needed.
__global__ __launch_bounds__(256, 8) void mainfill_kernel(const float* __restrict__ Hxs,
                                                          const int* __restrict__ H,
                                                          const float* __restrict__ prior_eps,
                                                          const float* __restrict__ Tprod,
                                                          const int* __restrict__ flag,
                                                          float* __restrict__ out,
                                                          int* __restrict__ counter,
                                                          int* __restrict__ worklist) {
    const int t = threadIdx.x;
    const int w = t >> 6;                 // 0..3
    const int lane = t & 63;
    const int half = w & 1;
    const int k = blockIdx.x * 2 + (w >> 1);

    const bool fast = (*flag == 0);
    const i32x4* H4  = reinterpret_cast<const i32x4*>(H + (size_t)k * N_DIM);
    const f32x4* TP4 = reinterpret_cast<const f32x4*>(Tprod);
    const f32x4* PE4 = reinterpret_cast<const f32x4*>(prior_eps);
    const f32x4* HX4 = reinterpret_cast<const f32x4*>(Hxs + (size_t)k * N_DIM);

    // ---- half-row prefix product: 2 int4 chunks (512 cols) ----
    float lp0 = 1.f, lp1 = 1.f;
    #pragma unroll
    for (int u = 0; u < 2; ++u) {
        const int idx = half * 128 + u * 64 + lane;     // int4 idx in [0,256)
        const i32x4 hh = H4[idx];
        float f;
        if (fast) {
            const f32x4 tv = TP4[idx];
            float f0 = hh.x ? tv.x : 1.f;
            float f1 = hh.y ? tv.y : 1.f;
            float f2 = hh.z ? tv.z : 1.f;
            float f3 = hh.w ? tv.w : 1.f;
            f = (f0 * f1) * (f2 * f3);
        } else {
            const f32x4 pe = PE4[idx];
            const f32x4 hx = HX4[idx];
            float t0 = fast_tanh_half((hh.x ? pe.x : 0.f) - hx.x);
            float t1 = fast_tanh_half((hh.y ? pe.y : 0.f) - hx.y);
            float t2 = fast_tanh_half((hh.z ? pe.z : 0.f) - hx.z);
            float t3 = fast_tanh_half((hh.w ? pe.w : 0.f) - hx.w);
            t0 = (t0 == 0.f) ? 1.f : t0;
            t1 = (t1 == 0.f) ? 1.f : t1;
            t2 = (t2 == 0.f) ? 1.f : t2;
            t3 = (t3 == 0.f) ? 1.f : t3;
            f = (t0 * t1) * (t2 * t3);
        }
        if (u == 0) lp0 *= f;
        else        lp1 *= f;
    }
    float hp = lp0 * lp1;
    #pragma unroll
    for (int off = 1; off < 64; off <<= 1)
        hp *= __shfl_xor(hp, off);

    __shared__ float sh[4];
    if (lane == 0) sh[w] = hp;
    __syncthreads();                       // the only barrier
    const float pp = sh[w & 2] * sh[(w & 2) | 1];

    if (pp == 0.0f) {
        // Full product exactly 0 -> whole row exactly 0. Plain-store stream.
        f32x4* orow = reinterpret_cast<f32x4*>(out + (size_t)k * N_DIM);
        const f32x4 z = {0.f, 0.f, 0.f, 0.f};
        #pragma unroll
        for (int s = 0; s < 16; ++s)
            orow[half * 1024 + s * 64 + lane] = z;
    } else if (half == 0 && lane == 0) {
        int i = atomicAdd(counter, 1);
        worklist[i] = k;
    }
}

// D4: tailfix -- early-exit on fast path; full general path otherwise.
__global__ __launch_bounds__(256) void tailfix_kernel(const float* __restrict__ Hxs,
                                                      const int* __restrict__ H,
                                                      const int* __restrict__ x,
                                                      const float* __restrict__ Min,
                                                      const float* __restrict__ dope,
                                                      float* __restrict__ prior_eps,
                                                      float* __restrict__ partial1,
                                                      float* __restrict__ colsum_new,
                                                      const int* __restrict__ counter,
                                                      const int* __restrict__ worklist,
                                                      float* __restrict__ out,
                                                      float* __restrict__ Mout,
                                                      unsigned* __restrict__ bar) {
    const int cnt = *counter;
    if (cnt == 0) return;                  // fast path: zeros + optimistic Mout stand

    const int b = blockIdx.x;
    const int t = threadIdx.x;
    const int lane = t & 63;

    // E: tail colsum (cols PREFIX:N), 16 rows per block.
    {
        const f32x4* p = reinterpret_cast<const f32x4*>(Hxs + (size_t)b * 16 * N_DIM + PREFIX);
        f32x4 acc[7];
        #pragma unroll
        for (int c = 0; c < 7; ++c) acc[c] = (f32x4){0.f, 0.f, 0.f, 0.f};
        for (int r = 0; r < 16; ++r) {
            #pragma unroll
            for (int c = 0; c < 7; ++c) {
                f32x4 v = p[(size_t)r * (N_DIM / 4) + c * 256 + t];
                acc[c].x += v.x; acc[c].y += v.y; acc[c].z += v.z; acc[c].w += v.w;
            }
        }
        f32x4* pr = reinterpret_cast<f32x4*>(partial1 + (size_t)b * TAILC);
        #pragma unroll
        for (int c = 0; c < 7; ++c) pr[c * 256 + t] = acc[c];
    }
    grid_barrier(bar, 0, TRB);

    // F: tail prep -> prior_eps for cols PREFIX:N.
    if (b < 28) {
        const int j = b * 256 + t;
        const int n = PREFIX + j;
        float cs = 0.0f;
        #pragma unroll 8
        for (int i = 0; i < TRB; ++i)
            cs += partial1[(size_t)i * TAILC + j];
        float m0 = Min[2 * n], m1 = Min[2 * n + 1];
        float m1n = m1 / (m0 + m1);
        float phi = logf(1.0f - m1n) - logf(m1n);
        float prior = dope[n] + phi + cs;
        prior = fminf(fmaxf(prior, -100.0f), 100.0f);
        prior_eps[n] = prior + 1e-4f;
    }
    grid_barrier(bar, 1, TRB);

    // G: fixup worklist rows (full general path; writes ALL columns).
    {
        const int wg = b * 4 + (t >> 6);
        for (int i = wg; i < cnt; i += TRB * 4) {
            const int k = worklist[i];
            const i32x4* H4  = reinterpret_cast<const i32x4*>(H + (size_t)k * N_DIM);
            const f32x4* PE4 = reinterpret_cast<const f32x4*>(prior_eps);
            const f32x4* HX4 = reinterpret_cast<const f32x4*>(Hxs + (size_t)k * N_DIM);

            float lp = 1.0f;
            for (int s = 0; s < 32; ++s) {
                const int idx = s * 64 + lane;
                const i32x4 hh = H4[idx];
                const f32x4 pe = PE4[idx];
                const f32x4 hx = HX4[idx];
                float t0 = fast_tanh_half((hh.x ? pe.x : 0.f) - hx.x);
                float t1 = fast_tanh_half((hh.y ? pe.y : 0.f) - hx.y);
                float t2 = fast_tanh_half((hh.z ? pe.z : 0.f) - hx.z);
                float t3 = fast_tanh_half((hh.w ? pe.w : 0.f) - hx.w);
                t0 = (t0 == 0.f) ? 1.f : t0;
                t1 = (t1 == 0.f) ? 1.f : t1;
                t2 = (t2 == 0.f) ? 1.f : t2;
                t3 = (t3 == 0.f) ? 1.f : t3;
                lp *= (t0 * t1) * (t2 * t3);
            }
            #pragma unroll
            for (int off = 1; off < 64; off <<= 1)
                lp *= __shfl_xor(lp, off);

            const float sgn = 1.0f - 2.0f * (float)x[k];
            const float P = sgn * lp;

            f32x4* orow = reinterpret_cast<f32x4*>(out + (size_t)k * N_DIM);
            for (int s = 0; s < 32; ++s) {
                const int idx = s * 64 + lane;
                const i32x4 hh = H4[idx];
                const f32x4 pe = PE4[idx];
                const f32x4 hx = HX4[idx];
                float t0 = fast_tanh_half((hh.x ? pe.x : 0.f) - hx.x);
                float t1 = fast_tanh_half((hh.y ? pe.y : 0.f) - hx.y);
                float t2 = fast_tanh_half((hh.z ? pe.z : 0.f) - hx.z);
                float t3 = fast_tanh_half((hh.w ? pe.w : 0.f) - hx.w);
                f32x4 o;
                o.x = check_msg(t0, P);
                o.y = check_msg(t1, P);
                o.z = check_msg(t2, P);
                o.w = check_msg(t3, P);
                orow[idx] = o;
                const int n0 = idx * 4;
                if (o.x != 0.f) atomicAdd(&colsum_new[n0 + 0], o.x);
                if (o.y != 0.f) atomicAdd(&colsum_new[n0 + 1], o.y);
                if (o.z != 0.f) atomicAdd(&colsum_new[n0 + 2], o.z);
                if (o.w != 0.f) atomicAdd(&colsum_new[n0 + 3], o.w);
            }
        }
    }
    grid_barrier(bar, 2, TRB);

    // H: rewrite Mout with the true colsum_new.
    if (b < 32) {
        const int n = b * 256 + t;
        float z = (1.0f - tanhf((colsum_new[n] + dope[n]) * 0.5f)) * 0.5f;
        float2 m; m.x = 1.0f - z; m.y = z;
        reinterpret_cast<float2*>(Mout)[n] = m;
    }
}

extern "C" void kernel_launch(void* const* d_in, const int* in_sizes, int n_in,
                              void* d_out, int out_size, void* d_ws, size_t ws_size,
                              hipStream_t stream) {
    (void)in_sizes; (void)n_in; (void)out_size; (void)ws_size;
    const float* ps  = (const float*)d_in[0];
    const float* Min = (const float*)d_in[1];
    const float* Hxs = (const float*)d_in[2];
    const int*   x   = (const int*)d_in[3];
    const int*   H   = (const int*)d_in[4];

    float* out = (float*)d_out;
    float* Mout = out;                       // N*2 floats
    float* Hxs_new = out + 2 * N_DIM;        // K*N floats

    unsigned* bar     = (unsigned*)d_ws;                      // 64 uints
    float* partial0   = (float*)d_ws + 64;                    // PCB*PREFIX (1 MB)
    float* partial1   = partial0 + (size_t)PCB * PREFIX;      // TRB*TAILC (7 MB)
    float* prior_eps  = partial1 + (size_t)TRB * TAILC;       // N
    float* dope       = prior_eps + N_DIM;                    // N
    float* Tprod      = dope + N_DIM;                         // PREFIX
    float* colsum_new = Tprod + PREFIX;                       // N
    int*   flag       = (int*)(colsum_new + N_DIM);
    int*   counter    = flag + 64;
    int*   worklist   = counter + 64;                         // K ints
    int*   nzp        = worklist + K_DIM;                     // PCB ints

    prefix_colsum_kernel<<<PCB, 256, 0, stream>>>(Hxs, partial0, nzp);

    prep_kernel<<<N_DIM / 256, 256, 0, stream>>>(ps, Min, partial0, nzp,
                                                 prior_eps, dope, Tprod,
                                                 colsum_new, Mout, flag,
                                                 counter, bar);

    mainfill_kernel<<<K_DIM / 2, 256, 0, stream>>>(Hxs, H, prior_eps, Tprod,
                                                   flag, Hxs_new, counter,
                                                   worklist);

    tailfix_kernel<<<TRB, 256, 0, stream>>>(Hxs, H, x, Min, dope, prior_eps,
                                            partial1, colsum_new, counter,
                                            worklist, Hxs_new, Mout, bar);
}